// Round 13
// baseline (181.569 us; speedup 1.0000x reference)
//
#include <hip/hip_runtime.h>
#include <hip/hip_bf16.h>

typedef __hip_bfloat16 bf16;
typedef __attribute__((ext_vector_type(8))) short bf16x8;
typedef __attribute__((ext_vector_type(4))) float f32x4;
typedef __attribute__((ext_vector_type(16))) float f32x16;

#define T_SEQ 2048
#define NHEADS 16
#define DK 64
#define DMODEL 1024

__device__ inline void load_lds16(const void* g, void* l) {
    __builtin_amdgcn_global_load_lds((const __attribute__((address_space(1))) void*)g,
                                     (__attribute__((address_space(3))) void*)l, 16, 0, 0);
}

__device__ inline unsigned pk_bf16(float lo, float hi) {
    unsigned a = __bfloat16_as_ushort(__float2bfloat16(lo));
    unsigned b = __bfloat16_as_ushort(__float2bfloat16(hi));
    return a | (b << 16);
}

// ---- fp32 -> bf16 convert (x + weights) + zero-fill of Oacc/Lacc tail ------
__global__ void cvt_all(const float* __restrict__ x,  const float* __restrict__ wq,
                        const float* __restrict__ wk, const float* __restrict__ wv,
                        const float* __restrict__ wo, bf16* __restrict__ xb,
                        bf16* __restrict__ wqkvb, bf16* __restrict__ wob,
                        float4* __restrict__ zacc) {
    int i = blockIdx.x * blockDim.x + threadIdx.x;
    if (i >= (1 << 21)) {                            // zero tail: Oacc+Lacc
        zacc[i - (1 << 21)] = make_float4(0.f, 0.f, 0.f, 0.f);
        return;
    }
    const float* src; bf16* dst; int off;
    if (i < (1 << 20)) { src = x; dst = xb; off = i; }
    else {
        int j = i - (1 << 20);
        int seg = j >> 18; off = j & ((1 << 18) - 1);
        src = (seg == 0) ? wq : (seg == 1) ? wk : (seg == 2) ? wv : wo;
        dst = (seg < 3) ? (wqkvb + ((size_t)seg << 20)) : wob;
    }
    float4 f = ((const float4*)src)[off];
    ushort4 o;
    o.x = __bfloat16_as_ushort(__float2bfloat16(f.x));
    o.y = __bfloat16_as_ushort(__float2bfloat16(f.y));
    o.z = __bfloat16_as_ushort(__float2bfloat16(f.z));
    o.w = __bfloat16_as_ushort(__float2bfloat16(f.w));
    ((ushort4*)dst)[off] = o;
}

// ---------------- GEMM1: qkv = x * Wqkv^T, fused RoPE + head split ----------
// v20 (swapped MFMA operands, register-local RoPE pairs) — unchanged.
__global__ __launch_bounds__(256, 4) void gemm_qkv_rope(const bf16* __restrict__ A,
                                                        const bf16* __restrict__ B,
                                                        bf16* __restrict__ qb,
                                                        bf16* __restrict__ kb,
                                                        bf16* __restrict__ vt) {
    const int K = 1024;
    __shared__ bf16 As[128 * 64];
    __shared__ bf16 Bs[128 * 64];
    const int tid  = threadIdx.x;
    const int lane = tid & 63;
    const int wave = tid >> 6;
    const int l16  = lane & 15;
    const int quad = lane >> 4;
    const int wy = wave >> 1, wx = wave & 1;
    const int brow = blockIdx.y * 128;
    const int bcol = blockIdx.x * 128;
    const int sw0 = (quad ^ (l16 & 7)) * 8;
    const int sw1 = ((4 + quad) ^ (l16 & 7)) * 8;

    f32x4 acc[4][4] = {};

    for (int k0 = 0; k0 < K; k0 += 64) {
#pragma unroll
        for (int i = 0; i < 4; ++i) {
            int j   = tid + 256 * i;                  // 0..1023
            int row = j >> 3;
            int blk = (j & 7) ^ (row & 7);            // pre-swizzled source blk
            load_lds16(A + (size_t)(brow + row) * K + k0 + blk * 8, (char*)As + j * 16);
            load_lds16(B + (size_t)(bcol + row) * K + k0 + blk * 8, (char*)Bs + j * 16);
        }
        __syncthreads();
#pragma unroll
        for (int ks = 0; ks < 2; ++ks) {
            const int sw = ks ? sw1 : sw0;
            bf16x8 af[4], bq[4];
#pragma unroll
            for (int i = 0; i < 4; ++i)
                af[i] = *(const bf16x8*)(As + (wy * 64 + i * 16 + l16) * 64 + sw);
#pragma unroll
            for (int j = 0; j < 4; ++j)
                bq[j] = *(const bf16x8*)(Bs + (wx * 64 + j * 16 + l16) * 64 + sw);
#pragma unroll
            for (int i = 0; i < 4; ++i)
#pragma unroll
                for (int j = 0; j < 4; ++j)
                    acc[i][j] = __builtin_amdgcn_mfma_f32_16x16x32_bf16(bq[j], af[i], acc[i][j], 0, 0, 0);
        }
        __syncthreads();
    }
    const int seg = bcol >> 10;                       // uniform per block
    const int hh  = ((bcol & 1023) >> 6) + wx;        // head index
    if (seg < 2) {
        bf16* dst = seg ? kb : qb;
        // q pre-scaled so attn computes p = exp2(q'.k) directly
        const float osc = seg ? 1.0f : 0.18033688011112042f;  // log2(e)/8
#pragma unroll
        for (int i = 0; i < 4; ++i) {
            int trow = brow + wy * 64 + i * 16 + l16;
            int t = trow & (T_SEQ - 1), bi = trow >> 11;
            float tf = (float)t;
            bf16* base = dst + ((size_t)(bi * NHEADS + hh) * T_SEQ + t) * DK;
#pragma unroll
            for (int j = 0; j < 4; ++j) {
                ushort4 u;
#pragma unroll
                for (int p = 0; p < 2; ++p) {
                    // d_pair = j*8 + quad*2 + p ; inv = 1000^(-d_pair/32)
                    const float inv = exp2f(-0.31143075889f * (float)(j * 8 + quad * 2 + p));
                    float s, c;
                    __sincosf(tf * inv, &s, &c);
                    float xe = acc[i][j][2 * p], xo = acc[i][j][2 * p + 1];
                    float re = fmaf(-xo, s, xe * c) * osc;
                    float ro = fmaf(xe, s, xo * c) * osc;
                    ((unsigned short*)&u)[2 * p] =
                        __bfloat16_as_ushort(__float2bfloat16(re));
                    ((unsigned short*)&u)[2 * p + 1] =
                        __bfloat16_as_ushort(__float2bfloat16(ro));
                }
                *(ushort4*)(base + j * 16 + quad * 4) = u;   // 4 consecutive d
            }
        }
    } else {
        // v: lane dim (l16 over i) = t -> coalesced vt stores (v14-verified)
#pragma unroll
        for (int j = 0; j < 4; ++j)
#pragma unroll
            for (int i = 0; i < 4; ++i)
#pragma unroll
                for (int r = 0; r < 4; ++r) {
                    int d    = j * 16 + quad * 4 + r;          // dk within head
                    int tcol = brow + wy * 64 + i * 16 + l16;
                    int t = tcol & (T_SEQ - 1), bi = tcol >> 11;
                    vt[((size_t)(bi * NHEADS + hh) * DK + d) * T_SEQ + t] =
                        __float2bfloat16(acc[i][j][r]);
                }
    }
}

// ---------------- GEMM: C[M,N] = A[M,K] * B[N,K]^T (fp32 out) ----------------
// v16 (BN=128) — unchanged.
__global__ __launch_bounds__(256, 4) void gemm_bt(const bf16* __restrict__ A,
                                                  const bf16* __restrict__ B,
                                                  float* __restrict__ C,
                                                  int M, int N, int K) {
    __shared__ bf16 As[128 * 64];
    __shared__ bf16 Bs[128 * 64];
    const int tid  = threadIdx.x;
    const int lane = tid & 63;
    const int wave = tid >> 6;
    const int l16  = lane & 15;
    const int quad = lane >> 4;
    const int wy = wave >> 1, wx = wave & 1;
    const int brow = blockIdx.y * 128;
    const int bcol = blockIdx.x * 128;
    const int sw0 = (quad ^ (l16 & 7)) * 8;
    const int sw1 = ((4 + quad) ^ (l16 & 7)) * 8;

    f32x4 acc[4][4] = {};

    for (int k0 = 0; k0 < K; k0 += 64) {
#pragma unroll
        for (int i = 0; i < 4; ++i) {
            int j   = tid + 256 * i;
            int row = j >> 3;
            int blk = (j & 7) ^ (row & 7);
            load_lds16(A + (size_t)(brow + row) * K + k0 + blk * 8, (char*)As + j * 16);
            load_lds16(B + (size_t)(bcol + row) * K + k0 + blk * 8, (char*)Bs + j * 16);
        }
        __syncthreads();
#pragma unroll
        for (int ks = 0; ks < 2; ++ks) {
            const int sw = ks ? sw1 : sw0;
            bf16x8 af[4], bq[4];
#pragma unroll
            for (int i = 0; i < 4; ++i)
                af[i] = *(const bf16x8*)(As + (wy * 64 + i * 16 + l16) * 64 + sw);
#pragma unroll
            for (int j = 0; j < 4; ++j)
                bq[j] = *(const bf16x8*)(Bs + (wx * 64 + j * 16 + l16) * 64 + sw);
#pragma unroll
            for (int i = 0; i < 4; ++i)
#pragma unroll
                for (int j = 0; j < 4; ++j)
                    acc[i][j] = __builtin_amdgcn_mfma_f32_16x16x32_bf16(af[i], bq[j], acc[i][j], 0, 0, 0);
        }
        __syncthreads();
    }
#pragma unroll
    for (int i = 0; i < 4; ++i)
#pragma unroll
        for (int j = 0; j < 4; ++j)
#pragma unroll
            for (int r = 0; r < 4; ++r) {
                int row = brow + wy * 64 + i * 16 + quad * 4 + r;
                int col = bcol + wx * 64 + j * 16 + l16;
                C[(size_t)row * N + col] = acc[i][j][r];
            }
}

// ---------------- flash attention v22: 32x32 MFMA, in-register P (T12) ------
// Swapped QK (mfma(K,Q), 32x32x16): C col = lane&31 = q, row = crow(r,hi) =
// key (HW-verified mapping) -> each lane's P slice is lane-local. PV A-frag
// needs P[q][k=hi*8+e]: assembled from packed bf16 pairs + ONE half-wave
// exchange (shfl_xor 32) -> the entire P LDS buffer + 12 DS ops/iter + two
// write->read stalls are gone. l-sum = ones-MFMA (C rows match O rows).
// Schedule (v16 parcels), K/V staging + swizzle, counted-vmcnt pipeline, and
// partial-tile atomics unchanged. Per wave: 32 queries (qr = qbase+wave*32).
__constant__ unsigned char c_sched[24] = {
    28, 61, 57, 58, 24, 53, 49, 20,
    62, 54, 50, 41, 42, 16, 45, 46,
     0,  4,  8, 12, 33, 37, 34, 38};

__global__ __launch_bounds__(256, 3) void attn_kernel(const bf16* __restrict__ qb,
                                                      const bf16* __restrict__ kb,
                                                      const bf16* __restrict__ vt,
                                                      float* __restrict__ Oacc,
                                                      float* __restrict__ Lacc,
                                                      bf16* __restrict__ conc) {
    __shared__ bf16 Ks[2][64 * 64];                // 2 x 8 KB
    __shared__ bf16 Vs[2][64 * 64];                // 2 x 8 KB
    const int bh = blockIdx.y;
    const int b = bh >> 4, h = bh & 15;

    const int e    = c_sched[blockIdx.x];
    const int tile = e >> 2, mode = e & 3;
    const int it0  = (mode == 2) ? tile + 1 : 0;
    const int it1  = (mode == 1) ? tile : 2 * tile + 1;
    const bool partial = (mode != 0);
    const int qbase = tile << 7;                   // 128 queries per tile

    const int tid = threadIdx.x;
    const int lane = tid & 63, wave = tid >> 6;
    const int l31 = lane & 31, hi = lane >> 5;
    const int qr = qbase + wave * 32;              // this wave's 32 queries

    const bf16* Qp = qb + (size_t)bh * T_SEQ * DK;
    const bf16* Kp = kb + (size_t)bh * T_SEQ * DK;
    const bf16* Vp = vt + (size_t)bh * DK * T_SEQ;

    // ones B-fragment for the l row-sum MFMA
    const short one_bits = 0x3F80;
    const bf16x8 ones = {one_bits, one_bits, one_bits, one_bits,
                         one_bits, one_bits, one_bits, one_bits};

    // Q as B-operand (32x32x16): col = l31 = q, k = hi*8+e (step s: +16s)
    bf16x8 qf[4];
#pragma unroll
    for (int s = 0; s < 4; ++s)
        qf[s] = *(const bf16x8*)(Qp + (size_t)(qr + l31) * DK + s * 16 + hi * 8);

    // stage row-major 64x64 tile with XOR-swizzled 16B col-blocks.
    // 4 load_lds16 per THREAD per stage -> vmcnt delta of 4 per wave.
    auto stage = [&](int bb, int k0) {
        int j = tid;
#pragma unroll
        for (int i = 0; i < 2; ++i, j += 256) {
            int row = j >> 3, cbl = (j & 7) ^ ((j >> 3) & 7);
            load_lds16(Kp + (size_t)(k0 + row) * DK + cbl * 8, (char*)Ks[bb] + j * 16);
        }
        j = tid;
#pragma unroll
        for (int i = 0; i < 2; ++i, j += 256) {
            int row = j >> 3, cbl = (j & 7) ^ ((j >> 3) & 7);
            load_lds16(Vp + (size_t)row * T_SEQ + k0 + cbl * 8, (char*)Vs[bb] + j * 16);
        }
    };

    f32x16 o0 = {}, o1 = {};       // O[q=crow(r,hi)][d = j*32 + l31]
    f32x16 ol = {};                // l row-sums, same C rows as o0/o1

    int cur = 0;
    stage(0, it0 * 64);
    if (it0 < it1) stage(1, (it0 + 1) * 64);
    for (int it = it0; it <= it1; ++it) {
        if (it < it1) asm volatile("s_waitcnt vmcnt(4)" ::: "memory");
        else          asm volatile("s_waitcnt vmcnt(0)" ::: "memory");
        __builtin_amdgcn_s_barrier();          // all waves' cur loads landed
        __builtin_amdgcn_sched_barrier(0);     // pin ds_reads below barrier

        const int k0 = it * 64;
#pragma unroll
        for (int sub = 0; sub < 2; ++sub) {
            const int kb0 = k0 + sub * 32;
            if (kb0 > qr + 31) continue;               // wave-uniform skip
            const int krow = sub * 32 + l31;

            // S^T = K Q^T : A=K (row=key), B=Q (col=q); 4 steps over dk=64
            f32x16 sacc = {};
            __builtin_amdgcn_s_setprio(1);
#pragma unroll
            for (int s = 0; s < 4; ++s) {
                bf16x8 kf = *(const bf16x8*)((char*)Ks[cur] + krow * 128 +
                                             (((2 * s + hi) ^ (krow & 7)) << 4));
                sacc = __builtin_amdgcn_mfma_f32_32x32x16_bf16(kf, qf[s], sacc, 0, 0, 0);
            }
            __builtin_amdgcn_s_setprio(0);

            // mask + exp, all in-register: p[r] for key = kb0 + crow(r,hi)
            const bool diagS = (kb0 + 31) > qr;
            float p[16];
#pragma unroll
            for (int r = 0; r < 16; ++r) {
                float v = sacc[r];
                if (diagS && (kb0 + (r & 3) + 8 * (r >> 2) + 4 * hi > qr + l31))
                    v = -30.0f;
                p[r] = exp2f(v);
            }

            // assemble PV A-fragments: frag[kh] elem e = P[q][k16 = hi*8+e]
            // own values: kappa(m) = (m&3) + 8*(m>>2) + 4*hi  (m = r - 8*kh)
            bf16x8 pa[2];
#pragma unroll
            for (int kh = 0; kh < 2; ++kh) {
                unsigned a0 = pk_bf16(p[8 * kh + 0], p[8 * kh + 1]);
                unsigned a1 = pk_bf16(p[8 * kh + 2], p[8 * kh + 3]);
                unsigned b0 = pk_bf16(p[8 * kh + 4], p[8 * kh + 5]);
                unsigned b1 = pk_bf16(p[8 * kh + 6], p[8 * kh + 7]);
                unsigned t0 = hi ? a0 : b0;            // what partner needs
                unsigned t1 = hi ? a1 : b1;
                unsigned x0 = (unsigned)__shfl_xor((int)t0, 32);
                unsigned x1 = (unsigned)__shfl_xor((int)t1, 32);
                union { unsigned u[4]; bf16x8 v; } pu;
                pu.u[0] = hi ? x0 : a0;
                pu.u[1] = hi ? x1 : a1;
                pu.u[2] = hi ? b0 : x0;
                pu.u[3] = hi ? b1 : x1;
                pa[kh] = pu.v;
            }

            // l-sum + PV (V as B-operand: col = d, k = key16)
            __builtin_amdgcn_s_setprio(1);
            ol = __builtin_amdgcn_mfma_f32_32x32x16_bf16(pa[0], ones, ol, 0, 0, 0);
            ol = __builtin_amdgcn_mfma_f32_32x32x16_bf16(pa[1], ones, ol, 0, 0, 0);
#pragma unroll
            for (int j = 0; j < 2; ++j) {
                const int vrow = j * 32 + l31;
#pragma unroll
                for (int kh = 0; kh < 2; ++kh) {
                    bf16x8 vf = *(const bf16x8*)((char*)Vs[cur] + vrow * 128 +
                                 (((4 * sub + 2 * kh + hi) ^ (vrow & 7)) << 4));
                    if (j == 0)
                        o0 = __builtin_amdgcn_mfma_f32_32x32x16_bf16(pa[kh], vf, o0, 0, 0, 0);
                    else
                        o1 = __builtin_amdgcn_mfma_f32_32x32x16_bf16(pa[kh], vf, o1, 0, 0, 0);
                }
            }
            __builtin_amdgcn_s_setprio(0);
        }

        __builtin_amdgcn_sched_barrier(0);     // pin ds_reads above barrier
        __builtin_amdgcn_s_barrier();          // all waves done reading cur
        if (it + 2 <= it1) stage(cur, (it + 2) * 64);   // reuse cur for it+2
        cur ^= 1;
    }

    // epilogue: lane holds O[q=qr+crow(r,hi)][d=l31 and 32+l31], l=ol[r]
#pragma unroll
    for (int r = 0; r < 16; ++r) {
        const int q = qr + (r & 3) + 8 * (r >> 2) + 4 * hi;
        if (!partial) {
            float inv_l = 1.0f / ol[r];
            size_t base = ((size_t)b * T_SEQ + q) * DMODEL + h * DK;
            conc[base + l31]      = __float2bfloat16(o0[r] * inv_l);
            conc[base + 32 + l31] = __float2bfloat16(o1[r] * inv_l);
        } else {
            if (l31 == 0)
                atomicAdd(&Lacc[(size_t)bh * 1024 + q - 1024], ol[r]);
            float* Ob = Oacc + ((size_t)bh * 1024 + q - 1024) * DK;
            atomicAdd(&Ob[l31], o0[r]);
            atomicAdd(&Ob[32 + l31], o1[r]);
        }
    }
}

// ---------------- normalize + concat (only q in [1024, 2048)) ----------------
__global__ void attn_finalize(const float* __restrict__ Oacc, const float* __restrict__ Lacc,
                              bf16* __restrict__ conc) {
    int i4 = blockIdx.x * blockDim.x + threadIdx.x;   // float4 units, 0..512K-1
    if (i4 >= (1 << 19)) return;
    int bhq = i4 >> 4;          // bh*1024 + q1
    int d4  = i4 & 15;
    int bh = bhq >> 10, q1 = bhq & 1023;
    int b = bh >> 4, h = bh & 15;
    int q = 1024 + q1;
    float inv = 1.0f / Lacc[bhq];
    float4 o4 = ((const float4*)Oacc)[i4];
    ushort4 u;
    u.x = __bfloat16_as_ushort(__float2bfloat16(o4.x * inv));
    u.y = __bfloat16_as_ushort(__float2bfloat16(o4.y * inv));
    u.z = __bfloat16_as_ushort(__float2bfloat16(o4.z * inv));
    u.w = __bfloat16_as_ushort(__float2bfloat16(o4.w * inv));
    *(ushort4*)&conc[((size_t)(b * T_SEQ + q)) * DMODEL + h * DK + d4 * 4] = u;
}

extern "C" void kernel_launch(void* const* d_in, const int* in_sizes, int n_in,
                              void* d_out, int out_size, void* d_ws, size_t ws_size,
                              hipStream_t stream) {
    const float* x  = (const float*)d_in[0];
    const float* wq = (const float*)d_in[1];
    const float* wk = (const float*)d_in[2];
    const float* wv = (const float*)d_in[3];
    const float* wo = (const float*)d_in[4];
    float* out = (float*)d_out;

    char* ws = (char*)d_ws;
    bf16* xb    = (bf16*)(ws);                      // 8 MiB  (4096x1024)
    bf16* wqkvb = (bf16*)(ws + (8ull << 20));       // 6 MiB  (3072x1024)
    bf16* wob   = (bf16*)(ws + (14ull << 20));      // 2 MiB  (1024x1024)
    bf16* conc  = (bf16*)(ws + (16ull << 20));      // 8 MiB
    float* Oacc = (float*)(ws + (24ull << 20));     // 8 MiB
    float* Lacc = (float*)(ws + (32ull << 20));     // 128 KiB (contiguous after Oacc)
    bf16* qb    = (bf16*)(ws + (40ull << 20));      // 8 MiB
    bf16* kb    = (bf16*)(ws + (48ull << 20));      // 8 MiB
    bf16* vt    = (bf16*)(ws + (56ull << 20));      // 8 MiB

    // 8192 cvt blocks + 2080 zero blocks (Oacc 8 MiB + Lacc 128 KiB)
    cvt_all<<<10272, 256, 0, stream>>>(x, wq, wk, wv, wo, xb, wqkvb, wob,
                                       (float4*)Oacc);
    gemm_qkv_rope<<<dim3(24, 32), 256, 0, stream>>>(xb, wqkvb, qb, kb, vt);

    attn_kernel<<<dim3(24, 32), 256, 0, stream>>>(qb, kb, vt, Oacc, Lacc, conc);
    attn_finalize<<<2048, 256, 0, stream>>>(Oacc, Lacc, conc);

    gemm_bt<<<dim3(8, 32), 256, 0, stream>>>(conc, wob, out, 4096, 1024, 1024);
}

// Round 14
// 179.846 us; speedup vs baseline: 1.0096x; 1.0096x over previous
//
#include <hip/hip_runtime.h>
#include <hip/hip_bf16.h>

typedef __hip_bfloat16 bf16;
typedef __attribute__((ext_vector_type(8))) short bf16x8;
typedef __attribute__((ext_vector_type(4))) float f32x4;

#define T_SEQ 2048
#define NHEADS 16
#define DK 64
#define DMODEL 1024

__device__ inline void load_lds16(const void* g, void* l) {
    __builtin_amdgcn_global_load_lds((const __attribute__((address_space(1))) void*)g,
                                     (__attribute__((address_space(3))) void*)l, 16, 0, 0);
}

// ---- fp32 -> bf16 convert (x + weights) + zero-fill of Oacc/Lacc tail ------
__global__ void cvt_all(const float* __restrict__ x,  const float* __restrict__ wq,
                        const float* __restrict__ wk, const float* __restrict__ wv,
                        const float* __restrict__ wo, bf16* __restrict__ xb,
                        bf16* __restrict__ wqkvb, bf16* __restrict__ wob,
                        float4* __restrict__ zacc) {
    int i = blockIdx.x * blockDim.x + threadIdx.x;
    if (i >= (1 << 21)) {                            // zero tail: Oacc+Lacc
        zacc[i - (1 << 21)] = make_float4(0.f, 0.f, 0.f, 0.f);
        return;
    }
    const float* src; bf16* dst; int off;
    if (i < (1 << 20)) { src = x; dst = xb; off = i; }
    else {
        int j = i - (1 << 20);
        int seg = j >> 18; off = j & ((1 << 18) - 1);
        src = (seg == 0) ? wq : (seg == 1) ? wk : (seg == 2) ? wv : wo;
        dst = (seg < 3) ? (wqkvb + ((size_t)seg << 20)) : wob;
    }
    float4 f = ((const float4*)src)[off];
    ushort4 o;
    o.x = __bfloat16_as_ushort(__float2bfloat16(f.x));
    o.y = __bfloat16_as_ushort(__float2bfloat16(f.y));
    o.z = __bfloat16_as_ushort(__float2bfloat16(f.z));
    o.w = __bfloat16_as_ushort(__float2bfloat16(f.w));
    ((ushort4*)dst)[off] = o;
}

// ---------------- GEMM1: qkv = x * Wqkv^T, fused RoPE + head split ----------
// v20 (swapped MFMA operands, register-local RoPE pairs) — unchanged.
__global__ __launch_bounds__(256, 4) void gemm_qkv_rope(const bf16* __restrict__ A,
                                                        const bf16* __restrict__ B,
                                                        bf16* __restrict__ qb,
                                                        bf16* __restrict__ kb,
                                                        bf16* __restrict__ vt) {
    const int K = 1024;
    __shared__ bf16 As[128 * 64];
    __shared__ bf16 Bs[128 * 64];
    const int tid  = threadIdx.x;
    const int lane = tid & 63;
    const int wave = tid >> 6;
    const int l16  = lane & 15;
    const int quad = lane >> 4;
    const int wy = wave >> 1, wx = wave & 1;
    const int brow = blockIdx.y * 128;
    const int bcol = blockIdx.x * 128;
    const int sw0 = (quad ^ (l16 & 7)) * 8;
    const int sw1 = ((4 + quad) ^ (l16 & 7)) * 8;

    f32x4 acc[4][4] = {};

    for (int k0 = 0; k0 < K; k0 += 64) {
#pragma unroll
        for (int i = 0; i < 4; ++i) {
            int j   = tid + 256 * i;                  // 0..1023
            int row = j >> 3;
            int blk = (j & 7) ^ (row & 7);            // pre-swizzled source blk
            load_lds16(A + (size_t)(brow + row) * K + k0 + blk * 8, (char*)As + j * 16);
            load_lds16(B + (size_t)(bcol + row) * K + k0 + blk * 8, (char*)Bs + j * 16);
        }
        __syncthreads();
#pragma unroll
        for (int ks = 0; ks < 2; ++ks) {
            const int sw = ks ? sw1 : sw0;
            bf16x8 af[4], bq[4];
#pragma unroll
            for (int i = 0; i < 4; ++i)
                af[i] = *(const bf16x8*)(As + (wy * 64 + i * 16 + l16) * 64 + sw);
#pragma unroll
            for (int j = 0; j < 4; ++j)
                bq[j] = *(const bf16x8*)(Bs + (wx * 64 + j * 16 + l16) * 64 + sw);
#pragma unroll
            for (int i = 0; i < 4; ++i)
#pragma unroll
                for (int j = 0; j < 4; ++j)
                    acc[i][j] = __builtin_amdgcn_mfma_f32_16x16x32_bf16(bq[j], af[i], acc[i][j], 0, 0, 0);
        }
        __syncthreads();
    }
    const int seg = bcol >> 10;                       // uniform per block
    const int hh  = ((bcol & 1023) >> 6) + wx;        // head index
    if (seg < 2) {
        bf16* dst = seg ? kb : qb;
        // q pre-scaled so attn computes p = exp2(q'.k) directly
        const float osc = seg ? 1.0f : 0.18033688011112042f;  // log2(e)/8
#pragma unroll
        for (int i = 0; i < 4; ++i) {
            int trow = brow + wy * 64 + i * 16 + l16;
            int t = trow & (T_SEQ - 1), bi = trow >> 11;
            float tf = (float)t;
            bf16* base = dst + ((size_t)(bi * NHEADS + hh) * T_SEQ + t) * DK;
#pragma unroll
            for (int j = 0; j < 4; ++j) {
                ushort4 u;
#pragma unroll
                for (int p = 0; p < 2; ++p) {
                    // d_pair = j*8 + quad*2 + p ; inv = 1000^(-d_pair/32)
                    const float inv = exp2f(-0.31143075889f * (float)(j * 8 + quad * 2 + p));
                    float s, c;
                    __sincosf(tf * inv, &s, &c);
                    float xe = acc[i][j][2 * p], xo = acc[i][j][2 * p + 1];
                    float re = fmaf(-xo, s, xe * c) * osc;
                    float ro = fmaf(xe, s, xo * c) * osc;
                    ((unsigned short*)&u)[2 * p] =
                        __bfloat16_as_ushort(__float2bfloat16(re));
                    ((unsigned short*)&u)[2 * p + 1] =
                        __bfloat16_as_ushort(__float2bfloat16(ro));
                }
                *(ushort4*)(base + j * 16 + quad * 4) = u;   // 4 consecutive d
            }
        }
    } else {
        // v: lane dim (l16 over i) = t -> coalesced vt stores (v14-verified)
#pragma unroll
        for (int j = 0; j < 4; ++j)
#pragma unroll
            for (int i = 0; i < 4; ++i)
#pragma unroll
                for (int r = 0; r < 4; ++r) {
                    int d    = j * 16 + quad * 4 + r;          // dk within head
                    int tcol = brow + wy * 64 + i * 16 + l16;
                    int t = tcol & (T_SEQ - 1), bi = tcol >> 11;
                    vt[((size_t)(bi * NHEADS + hh) * DK + d) * T_SEQ + t] =
                        __float2bfloat16(acc[i][j][r]);
                }
    }
}

// ---------------- GEMM: C[M,N] = A[M,K] * B[N,K]^T (fp32 out) ----------------
// v23: counted-vmcnt double-buffer (v21 attn structure). gemm_bt is the only
// kernel at 1 block/CU (zero cross-block latency hiding), so its 16 per-iter
// DMA drains were fully exposed. Prologue stages BOTH buffers; per iter:
// wait OWN 8 staging loads for cur (next tile's 8 stay in flight through the
// 32-MFMA compute) -> raw barrier -> compute -> barrier -> stage it+2 into
// cur's buffer. LDS 32->64 KB is free (occupancy is grid-bound at 1/CU).
__global__ __launch_bounds__(256, 2) void gemm_bt(const bf16* __restrict__ A,
                                                  const bf16* __restrict__ B,
                                                  float* __restrict__ C,
                                                  int M, int N, int K) {
    __shared__ bf16 As[2][128 * 64];
    __shared__ bf16 Bs[2][128 * 64];
    const int tid  = threadIdx.x;
    const int lane = tid & 63;
    const int wave = tid >> 6;
    const int l16  = lane & 15;
    const int quad = lane >> 4;
    const int wy = wave >> 1, wx = wave & 1;
    const int brow = blockIdx.y * 128;
    const int bcol = blockIdx.x * 128;
    const int sw0 = (quad ^ (l16 & 7)) * 8;
    const int sw1 = ((4 + quad) ^ (l16 & 7)) * 8;

    // 8 load_lds16 per THREAD per stage -> vmcnt delta of 8 per stage.
    auto stage = [&](int bb, int k0) {
#pragma unroll
        for (int i = 0; i < 4; ++i) {
            int j   = tid + 256 * i;
            int row = j >> 3;
            int blk = (j & 7) ^ (row & 7);
            load_lds16(A + (size_t)(brow + row) * K + k0 + blk * 8, (char*)As[bb] + j * 16);
            load_lds16(B + (size_t)(bcol + row) * K + k0 + blk * 8, (char*)Bs[bb] + j * 16);
        }
    };

    f32x4 acc[4][4] = {};

    int cur = 0;
    stage(0, 0);
    if (64 < K) stage(1, 64);
    for (int k0 = 0; k0 < K; k0 += 64) {
        if (k0 + 64 < K) asm volatile("s_waitcnt vmcnt(8)" ::: "memory");
        else             asm volatile("s_waitcnt vmcnt(0)" ::: "memory");
        __builtin_amdgcn_s_barrier();          // all waves' cur loads landed
        __builtin_amdgcn_sched_barrier(0);     // pin ds_reads below barrier
#pragma unroll
        for (int ks = 0; ks < 2; ++ks) {
            const int sw = ks ? sw1 : sw0;
            bf16x8 af[4], bq[4];
#pragma unroll
            for (int i = 0; i < 4; ++i)
                af[i] = *(const bf16x8*)(As[cur] + (wy * 64 + i * 16 + l16) * 64 + sw);
#pragma unroll
            for (int j = 0; j < 4; ++j)
                bq[j] = *(const bf16x8*)(Bs[cur] + (wx * 64 + j * 16 + l16) * 64 + sw);
#pragma unroll
            for (int i = 0; i < 4; ++i)
#pragma unroll
                for (int j = 0; j < 4; ++j)
                    acc[i][j] = __builtin_amdgcn_mfma_f32_16x16x32_bf16(af[i], bq[j], acc[i][j], 0, 0, 0);
        }
        __builtin_amdgcn_sched_barrier(0);     // pin ds_reads above barrier
        __builtin_amdgcn_s_barrier();          // all waves done reading cur
        if (k0 + 128 < K) stage(cur, k0 + 128);
        cur ^= 1;
    }
#pragma unroll
    for (int i = 0; i < 4; ++i)
#pragma unroll
        for (int j = 0; j < 4; ++j)
#pragma unroll
            for (int r = 0; r < 4; ++r) {
                int row = brow + wy * 64 + i * 16 + quad * 4 + r;
                int col = bcol + wx * 64 + j * 16 + l16;
                C[(size_t)row * N + col] = acc[i][j][r];
            }
}

// ---------------- flash attention v21 (REVERTED from v22) -------------------
// v22's 32x32 in-register P doubled bank conflicts (1.08M->2.13M: 32-lane
// reads span 32 rows but the swizzle only decorrelates 8-row stripes) and
// cost +3.6 us. The 16x16 + P-LDS structure with phase-conflict-free reads
// is the better trade on this geometry.
__constant__ unsigned char c_sched[24] = {
    28, 61, 57, 58, 24, 53, 49, 20,
    62, 54, 50, 41, 42, 16, 45, 46,
     0,  4,  8, 12, 33, 37, 34, 38};

__global__ __launch_bounds__(256, 4) void attn_kernel(const bf16* __restrict__ qb,
                                                      const bf16* __restrict__ kb,
                                                      const bf16* __restrict__ vt,
                                                      float* __restrict__ Oacc,
                                                      float* __restrict__ Lacc,
                                                      bf16* __restrict__ conc) {
    __shared__ bf16 Ks[2][64 * 64];                // 2 x 8 KB
    __shared__ bf16 Vs[2][64 * 64];                // 2 x 8 KB
    __shared__ bf16 Pl[4][16 * 64];                // 8 KB (per-wave, shared g0/g1)
    const int bh = blockIdx.y;
    const int b = bh >> 4, h = bh & 15;

    const int e    = c_sched[blockIdx.x];
    const int tile = e >> 2, mode = e & 3;
    const int it0  = (mode == 2) ? tile + 1 : 0;
    const int it1  = (mode == 1) ? tile : 2 * tile + 1;
    const bool partial = (mode != 0);
    const int qbase = tile << 7;                   // 128 queries per tile

    const int tid = threadIdx.x;
    const int lane = tid & 63, wave = tid >> 6;
    const int l16 = lane & 15, quad = lane >> 4;
    const int qr0 = qbase + wave * 16;             // group0 query rows
    const int qr1 = qr0 + 64;                      // group1 query rows

    const bf16* Qp = qb + (size_t)bh * T_SEQ * DK;
    const bf16* Kp = kb + (size_t)bh * T_SEQ * DK;
    const bf16* Vp = vt + (size_t)bh * DK * T_SEQ;
    char* Pw = (char*)&Pl[wave][0];

    // ones B-fragment for the l row-sum MFMA
    const short one_bits = 0x3F80;
    const bf16x8 ones = {one_bits, one_bits, one_bits, one_bits,
                         one_bits, one_bits, one_bits, one_bits};

    // Q as B-operand: n = query = l16, k = dk = quad*8+j (+32 per kstep)
    bf16x8 qf[2][2];
#pragma unroll
    for (int s = 0; s < 2; ++s) {
        qf[0][s] = *(const bf16x8*)(Qp + (size_t)(qr0 + l16) * DK + s * 32 + quad * 8);
        qf[1][s] = *(const bf16x8*)(Qp + (size_t)(qr1 + l16) * DK + s * 32 + quad * 8);
    }

    // stage row-major 64x64 tile with XOR-swizzled 16B col-blocks.
    // 4 load_lds16 per THREAD per stage -> vmcnt delta of 4 per stage per wave.
    auto stage = [&](int bb, int k0) {
        int j = tid;
#pragma unroll
        for (int i = 0; i < 2; ++i, j += 256) {
            int row = j >> 3, cbl = (j & 7) ^ ((j >> 3) & 7);
            load_lds16(Kp + (size_t)(k0 + row) * DK + cbl * 8, (char*)Ks[bb] + j * 16);
        }
        j = tid;
#pragma unroll
        for (int i = 0; i < 2; ++i, j += 256) {
            int row = j >> 3, cbl = (j & 7) ^ ((j >> 3) & 7);
            load_lds16(Vp + (size_t)row * T_SEQ + k0 + cbl * 8, (char*)Vs[bb] + j * 16);
        }
    };

    f32x4 o0[4] = {}, o1[4] = {};
    f32x4 ol0 = {}, ol1 = {};      // l row-sums (same C-rows as o*[j])
    const int sw0 = (quad ^ (l16 & 7)) * 8;
    const int sw1 = ((4 + quad) ^ (l16 & 7)) * 8;
    // P buffer addressing (bytes): row=l16 (128B), XOR-swizzled 16B blocks
    const int pw_wr_base = l16 * 128 + (quad & 1) * 8;   // + swizzled block
    const int pq = quad >> 1;

    int cur = 0;
    stage(0, it0 * 64);
    if (it0 < it1) stage(1, (it0 + 1) * 64);
    for (int it = it0; it <= it1; ++it) {
        // wait OWN staging loads for cur (oldest 4); next tile's 4 keep flying
        if (it < it1) asm volatile("s_waitcnt vmcnt(4)" ::: "memory");
        else          asm volatile("s_waitcnt vmcnt(0)" ::: "memory");
        __builtin_amdgcn_s_barrier();          // all waves' cur loads landed
        __builtin_amdgcn_sched_barrier(0);     // pin ds_reads below barrier

        const int k0 = it * 64;
        const bool skip0 = (k0 > qr0 + 15);             // wave-uniform
        const bool diag0 = (k0 + 63 > qr0) && !skip0;
        const bool diag1 = (k0 + 63 > qr1);             // skip1 never happens

        // S^T = K Q^T over 64 keys; kf fragments shared by both groups
        f32x4 s0[4] = {}, s1[4] = {};
        __builtin_amdgcn_s_setprio(1);
#pragma unroll
        for (int nt = 0; nt < 4; ++nt) {
            bf16x8 kf0 = *(const bf16x8*)(Ks[cur] + (nt * 16 + l16) * 64 + sw0);
            bf16x8 kf1 = *(const bf16x8*)(Ks[cur] + (nt * 16 + l16) * 64 + sw1);
            if (!skip0) {
                s0[nt] = __builtin_amdgcn_mfma_f32_16x16x32_bf16(kf0, qf[0][0], s0[nt], 0, 0, 0);
                s0[nt] = __builtin_amdgcn_mfma_f32_16x16x32_bf16(kf1, qf[0][1], s0[nt], 0, 0, 0);
            }
            s1[nt] = __builtin_amdgcn_mfma_f32_16x16x32_bf16(kf0, qf[1][0], s1[nt], 0, 0, 0);
            s1[nt] = __builtin_amdgcn_mfma_f32_16x16x32_bf16(kf1, qf[1][1], s1[nt], 0, 0, 0);
        }
        __builtin_amdgcn_s_setprio(0);

        // ---- group 0: exp -> P buffer -> PV (+ l-sum MFMA) ----
        if (!skip0) {
#pragma unroll
            for (int nt = 0; nt < 4; ++nt) {
                union { bf16 hv[4]; uint2 u; } pk;
#pragma unroll
                for (int r = 0; r < 4; ++r) {
                    float v = s0[nt][r];
                    if (diag0 && (k0 + nt * 16 + quad * 4 + r > qr0 + l16)) v = -30.0f;
                    pk.hv[r] = __float2bfloat16(exp2f(v));
                }
                *(uint2*)(Pw + pw_wr_base + (((nt * 2 + pq) ^ (l16 & 7)) << 4)) = pk.u;
            }
            __builtin_amdgcn_s_setprio(1);
#pragma unroll
            for (int ks = 0; ks < 2; ++ks) {
                bf16x8 pf = *(const bf16x8*)(Pw + l16 * 128 + (((ks * 4 + quad) ^ (l16 & 7)) << 4));
                const int sw = ks ? sw1 : sw0;
                ol0 = __builtin_amdgcn_mfma_f32_16x16x32_bf16(pf, ones, ol0, 0, 0, 0);
#pragma unroll
                for (int j = 0; j < 4; ++j) {
                    bf16x8 vf = *(const bf16x8*)(Vs[cur] + (j * 16 + l16) * 64 + sw);
                    o0[j] = __builtin_amdgcn_mfma_f32_16x16x32_bf16(pf, vf, o0[j], 0, 0, 0);
                }
            }
            __builtin_amdgcn_s_setprio(0);
        }

        // ---- group 1: exp -> P buffer (reused; per-wave DS pipe is in-order,
        // so these writes cannot pass g0's pf reads) -> PV (+ l-sum MFMA) ----
#pragma unroll
        for (int nt = 0; nt < 4; ++nt) {
            union { bf16 hv[4]; uint2 u; } pk;
#pragma unroll
            for (int r = 0; r < 4; ++r) {
                float v = s1[nt][r];
                if (diag1 && (k0 + nt * 16 + quad * 4 + r > qr1 + l16)) v = -30.0f;
                pk.hv[r] = __float2bfloat16(exp2f(v));
            }
            *(uint2*)(Pw + pw_wr_base + (((nt * 2 + pq) ^ (l16 & 7)) << 4)) = pk.u;
        }
        __builtin_amdgcn_s_setprio(1);
#pragma unroll
        for (int ks = 0; ks < 2; ++ks) {
            bf16x8 pf = *(const bf16x8*)(Pw + l16 * 128 + (((ks * 4 + quad) ^ (l16 & 7)) << 4));
            const int sw = ks ? sw1 : sw0;
            ol1 = __builtin_amdgcn_mfma_f32_16x16x32_bf16(pf, ones, ol1, 0, 0, 0);
#pragma unroll
            for (int j = 0; j < 4; ++j) {
                bf16x8 vf = *(const bf16x8*)(Vs[cur] + (j * 16 + l16) * 64 + sw);
                o1[j] = __builtin_amdgcn_mfma_f32_16x16x32_bf16(pf, vf, o1[j], 0, 0, 0);
            }
        }
        __builtin_amdgcn_s_setprio(0);

        __builtin_amdgcn_sched_barrier(0);     // pin ds_reads above barrier
        __builtin_amdgcn_s_barrier();          // all waves done reading cur
        if (it + 2 <= it1) stage(cur, (it + 2) * 64);   // reuse cur for it+2
        cur ^= 1;
    }

    // epilogue: ol*[r] is the full l for query qr + quad*4 + r (no shuffles)
#pragma unroll
    for (int g = 0; g < 2; ++g) {
        const f32x4* op = g ? o1 : o0;
        const f32x4 lv = g ? ol1 : ol0;
        const int qr = g ? qr1 : qr0;
        if (!partial) {
#pragma unroll
            for (int r = 0; r < 4; ++r) {
                float inv_l = 1.0f / lv[r];
                int t = qr + quad * 4 + r;
#pragma unroll
                for (int j = 0; j < 4; ++j)
                    conc[((size_t)b * T_SEQ + t) * DMODEL + h * DK + j * 16 + l16] =
                        __float2bfloat16(op[j][r] * inv_l);
            }
        } else {
#pragma unroll
            for (int r = 0; r < 4; ++r) {
                int q = qr + quad * 4 + r;
                if (l16 == 0)
                    atomicAdd(&Lacc[(size_t)bh * 1024 + q - 1024], lv[r]);
                float* Ob = Oacc + ((size_t)bh * 1024 + q - 1024) * DK;
#pragma unroll
                for (int j = 0; j < 4; ++j)
                    atomicAdd(&Ob[j * 16 + l16], op[j][r]);
            }
        }
    }
}

// ---------------- normalize + concat (only q in [1024, 2048)) ----------------
__global__ void attn_finalize(const float* __restrict__ Oacc, const float* __restrict__ Lacc,
                              bf16* __restrict__ conc) {
    int i4 = blockIdx.x * blockDim.x + threadIdx.x;   // float4 units, 0..512K-1
    if (i4 >= (1 << 19)) return;
    int bhq = i4 >> 4;          // bh*1024 + q1
    int d4  = i4 & 15;
    int bh = bhq >> 10, q1 = bhq & 1023;
    int b = bh >> 4, h = bh & 15;
    int q = 1024 + q1;
    float inv = 1.0f / Lacc[bhq];
    float4 o4 = ((const float4*)Oacc)[i4];
    ushort4 u;
    u.x = __bfloat16_as_ushort(__float2bfloat16(o4.x * inv));
    u.y = __bfloat16_as_ushort(__float2bfloat16(o4.y * inv));
    u.z = __bfloat16_as_ushort(__float2bfloat16(o4.z * inv));
    u.w = __bfloat16_as_ushort(__float2bfloat16(o4.w * inv));
    *(ushort4*)&conc[((size_t)(b * T_SEQ + q)) * DMODEL + h * DK + d4 * 4] = u;
}

extern "C" void kernel_launch(void* const* d_in, const int* in_sizes, int n_in,
                              void* d_out, int out_size, void* d_ws, size_t ws_size,
                              hipStream_t stream) {
    const float* x  = (const float*)d_in[0];
    const float* wq = (const float*)d_in[1];
    const float* wk = (const float*)d_in[2];
    const float* wv = (const float*)d_in[3];
    const float* wo = (const float*)d_in[4];
    float* out = (float*)d_out;

    char* ws = (char*)d_ws;
    bf16* xb    = (bf16*)(ws);                      // 8 MiB  (4096x1024)
    bf16* wqkvb = (bf16*)(ws + (8ull << 20));       // 6 MiB  (3072x1024)
    bf16* wob   = (bf16*)(ws + (14ull << 20));      // 2 MiB  (1024x1024)
    bf16* conc  = (bf16*)(ws + (16ull << 20));      // 8 MiB
    float* Oacc = (float*)(ws + (24ull << 20));     // 8 MiB
    float* Lacc = (float*)(ws + (32ull << 20));     // 128 KiB (contiguous after Oacc)
    bf16* qb    = (bf16*)(ws + (40ull << 20));      // 8 MiB
    bf16* kb    = (bf16*)(ws + (48ull << 20));      // 8 MiB
    bf16* vt    = (bf16*)(ws + (56ull << 20));      // 8 MiB

    // 8192 cvt blocks + 2080 zero blocks (Oacc 8 MiB + Lacc 128 KiB)
    cvt_all<<<10272, 256, 0, stream>>>(x, wq, wk, wv, wo, xb, wqkvb, wob,
                                       (float4*)Oacc);
    gemm_qkv_rope<<<dim3(24, 32), 256, 0, stream>>>(xb, wqkvb, qb, kb, vt);

    attn_kernel<<<dim3(24, 32), 256, 0, stream>>>(qb, kb, vt, Oacc, Lacc, conc);
    attn_finalize<<<2048, 256, 0, stream>>>(Oacc, Lacc, conc);

    gemm_bt<<<dim3(8, 32), 256, 0, stream>>>(conc, wob, out, 4096, 1024, 1024);
}